// Round 1
// baseline (2081.751 us; speedup 1.0000x reference)
//
#include <hip/hip_runtime.h>

typedef unsigned short u16;
typedef __attribute__((ext_vector_type(8))) short short8;
typedef __attribute__((ext_vector_type(4))) float f32x4;

__device__ inline u16 f2bf(float f){
  unsigned int u = __builtin_bit_cast(unsigned int, f);
  u += 0x7fffu + ((u >> 16) & 1u);
  return (u16)(u >> 16);
}
__device__ inline float bf2f(u16 h){
  unsigned int u = ((unsigned int)h) << 16;
  return __builtin_bit_cast(float, u);
}

// ---------------- weight transpose + cast:  W[K,N] f32 -> Wt[N,Kpad] bf16 ----
__global__ __launch_bounds__(256) void transpose_cast(
    const float* __restrict__ W, u16* __restrict__ Wt, int K, int N, int Kpad)
{
  __shared__ float tile[32][33];
  int k0 = blockIdx.x * 32, n0 = blockIdx.y * 32;
  int tx = threadIdx.x & 31, ty = threadIdx.x >> 5;   // ty 0..7
#pragma unroll
  for (int i = 0; i < 4; ++i) {
    int k = k0 + ty + i * 8;
    float v = 0.f;
    if (k < K && (n0 + tx) < N) v = W[(size_t)k * N + n0 + tx];
    tile[ty + i * 8][tx] = v;
  }
  __syncthreads();
#pragma unroll
  for (int i = 0; i < 4; ++i) {
    int nn = n0 + ty + i * 8;
    if (nn < N) Wt[(size_t)nn * Kpad + k0 + tx] = f2bf(tile[tx][ty + i * 8]);
  }
}

// ---------------- x cast with K padding -------------------------------------
__global__ void cast_pad(const float* __restrict__ x, u16* __restrict__ xb,
                         int R, int C, int Cp)
{
  int i = blockIdx.x * 256 + threadIdx.x;
  if (i >= R * Cp) return;
  int r = i / Cp, c = i % Cp;
  xb[i] = f2bf(c < C ? x[(size_t)r * C + c] : 0.f);
}

// ---------------- bf16 MFMA GEMM: C[M,N] = A[M,K] @ Bt[N,K]^T ---------------
// A,Bt row-major bf16 with row stride K. Epilogue: +bias, relu, bf16/f32 out.
#define LDSS 48   // LDS row stride in bf16 elems (96B: 16B-aligned, conflict-reducing)
__global__ __launch_bounds__(256) void gemm_bt(
    const u16* __restrict__ A, const u16* __restrict__ B,
    float* __restrict__ Cf, u16* __restrict__ Cb,
    const float* __restrict__ bias, int M, int N, int K, int relu)
{
  __shared__ u16 As[128 * LDSS];
  __shared__ u16 Bs[128 * LDSS];
  int tid = threadIdx.x;
  int wave = tid >> 6, lane = tid & 63;
  int wr = wave >> 1, wc = wave & 1;
  int tile_m = blockIdx.y * 128, tile_n = blockIdx.x * 128;

  f32x4 acc[4][4];
#pragma unroll
  for (int mi = 0; mi < 4; ++mi)
#pragma unroll
    for (int ni = 0; ni < 4; ++ni) { f32x4 z = {0.f,0.f,0.f,0.f}; acc[mi][ni] = z; }

  int srow = tid >> 2, scol = (tid & 3) * 8;
  int lrow = lane & 15, lk = (lane >> 4) * 8;

  for (int k0 = 0; k0 < K; k0 += 32) {
#pragma unroll
    for (int i = 0; i < 2; ++i) {
      int r = srow + i * 64;
      int gr = tile_m + r;
      short8 va = {0,0,0,0,0,0,0,0};
      if (gr < M) va = *reinterpret_cast<const short8*>(A + (size_t)gr * K + k0 + scol);
      *reinterpret_cast<short8*>(&As[r * LDSS + scol]) = va;
      short8 vb = *reinterpret_cast<const short8*>(B + (size_t)(tile_n + r) * K + k0 + scol);
      *reinterpret_cast<short8*>(&Bs[r * LDSS + scol]) = vb;
    }
    __syncthreads();
    short8 af[4], bfr[4];
#pragma unroll
    for (int mi = 0; mi < 4; ++mi)
      af[mi] = *reinterpret_cast<const short8*>(&As[(wr * 64 + mi * 16 + lrow) * LDSS + lk]);
#pragma unroll
    for (int ni = 0; ni < 4; ++ni)
      bfr[ni] = *reinterpret_cast<const short8*>(&Bs[(wc * 64 + ni * 16 + lrow) * LDSS + lk]);
#pragma unroll
    for (int mi = 0; mi < 4; ++mi)
#pragma unroll
      for (int ni = 0; ni < 4; ++ni)
        acc[mi][ni] = __builtin_amdgcn_mfma_f32_16x16x32_bf16(af[mi], bfr[ni], acc[mi][ni], 0, 0, 0);
    __syncthreads();
  }

  int rquad = (lane >> 4) * 4;
#pragma unroll
  for (int mi = 0; mi < 4; ++mi)
#pragma unroll
    for (int ni = 0; ni < 4; ++ni) {
      int col = tile_n + wc * 64 + ni * 16 + lrow;
      float bv = bias ? bias[col] : 0.f;
#pragma unroll
      for (int j = 0; j < 4; ++j) {
        int row = tile_m + wr * 64 + mi * 16 + rquad + j;
        if (row < M) {
          float v = acc[mi][ni][j] + bv;
          if (relu) v = fmaxf(v, 0.f);
          if (Cb) Cb[(size_t)row * N + col] = f2bf(v);
          else    Cf[(size_t)row * N + col] = v;
        }
      }
    }
}

// ---------------- attention scores: a_src/a_dst [N,4] -----------------------
__global__ __launch_bounds__(256) void attn_scores(
    const u16* __restrict__ h, const float* __restrict__ asrc,
    const float* __restrict__ adst, float* __restrict__ a_s, float* __restrict__ a_d)
{
  int n = blockIdx.x;
  int hh = threadIdx.x >> 6, lane = threadIdx.x & 63;
  const u16* hr = h + (size_t)n * 8192 + hh * 2048;
  const float* as = asrc + hh * 2048;
  const float* ad = adst + hh * 2048;
  float ssum = 0.f, dsum = 0.f;
#pragma unroll
  for (int i = 0; i < 4; ++i) {
    int c = lane * 8 + i * 512;
    short8 v = *reinterpret_cast<const short8*>(hr + c);
#pragma unroll
    for (int j = 0; j < 8; ++j) {
      float f = bf2f((u16)v[j]);
      ssum += f * as[c + j];
      dsum += f * ad[c + j];
    }
  }
  for (int off = 32; off; off >>= 1) {
    ssum += __shfl_down(ssum, off);
    dsum += __shfl_down(dsum, off);
  }
  if (lane == 0) { a_s[n * 4 + hh] = ssum; a_d[n * 4 + hh] = dsum; }
}

// ---------------- CSR build --------------------------------------------------
__global__ void zero_int(int* p, int n){ int i = blockIdx.x*256+threadIdx.x; if (i < n) p[i] = 0; }

__global__ void count_deg(const int* __restrict__ ei, int E, int Nn, int* __restrict__ deg){
  int e = blockIdx.x*256+threadIdx.x; if (e >= E + Nn) return;
  int d = (e < E) ? ei[E + e] : (e - E);
  atomicAdd(&deg[d], 1);
}

__global__ void scan_deg(const int* __restrict__ deg, int* __restrict__ row_st,
                         int* __restrict__ cursor, int Nn){
  __shared__ int partial[256];
  int tid = threadIdx.x;
  int chunk = (Nn + 255) / 256;
  int start = tid * chunk;
  int sum = 0;
  for (int i = 0; i < chunk; ++i) { int idx = start + i; if (idx < Nn) sum += deg[idx]; }
  partial[tid] = sum;
  __syncthreads();
  if (tid == 0) { int acc = 0; for (int i = 0; i < 256; ++i) { int t = partial[i]; partial[i] = acc; acc += t; } }
  __syncthreads();
  int acc = partial[tid];
  for (int i = 0; i < chunk; ++i) {
    int idx = start + i;
    if (idx < Nn) { row_st[idx] = acc; cursor[idx] = acc; acc += deg[idx]; }
  }
  if (tid == 255) row_st[Nn] = acc;
}

__global__ void scatter_edges(const int* __restrict__ ei, int E, int Nn,
                              int* __restrict__ cursor, int* __restrict__ srcs){
  int e = blockIdx.x*256+threadIdx.x; if (e >= E + Nn) return;
  int s = (e < E) ? ei[e]     : (e - E);
  int d = (e < E) ? ei[E + e] : (e - E);
  int pos = atomicAdd(&cursor[d], 1);
  srcs[pos] = s;
}

// ---------------- per-(node,head) edge softmax -------------------------------
__global__ void edge_softmax(const int* __restrict__ row_st, const int* __restrict__ srcs,
                             const float* __restrict__ a_s, const float* __restrict__ a_d,
                             float* __restrict__ alpha, int Nn){
  int t = blockIdx.x*256+threadIdx.x;
  if (t >= Nn * 4) return;
  int n = t >> 2, hh = t & 3;
  int b = row_st[n], e = row_st[n + 1];
  float ad = a_d[n * 4 + hh];
  float m = -1e30f;
  for (int p = b; p < e; ++p) {
    float x = a_s[srcs[p] * 4 + hh] + ad;
    x = x > 0.f ? x : 0.2f * x;
    alpha[p * 4 + hh] = x;
    m = fmaxf(m, x);
  }
  float ssum = 0.f;
  for (int p = b; p < e; ++p) {
    float ex = expf(alpha[p * 4 + hh] - m);
    alpha[p * 4 + hh] = ex;
    ssum += ex;
  }
  float inv = 1.f / (ssum + 1e-16f);
  for (int p = b; p < e; ++p) alpha[p * 4 + hh] *= inv;
}

// ---------------- aggregation: out[n] = sum alpha*h[src] + bias (bf16 out) ---
__global__ __launch_bounds__(256) void aggregate(
    const u16* __restrict__ h, const float* __restrict__ alpha,
    const int* __restrict__ row_st, const int* __restrict__ srcs,
    const float* __restrict__ bias, u16* __restrict__ out)
{
  int n = blockIdx.x, tid = threadIdx.x;
  float acc[32];
#pragma unroll
  for (int i = 0; i < 32; ++i) acc[i] = 0.f;
  int b = row_st[n], e = row_st[n + 1];
  for (int p = b; p < e; ++p) {
    int s = srcs[p];
    const u16* hr = h + (size_t)s * 8192;
    float al[4];
#pragma unroll
    for (int j = 0; j < 4; ++j) al[j] = alpha[p * 4 + j];
#pragma unroll
    for (int j = 0; j < 4; ++j) {
      short8 v = *reinterpret_cast<const short8*>(hr + (tid + j * 256) * 8);
      float a = al[j];
#pragma unroll
      for (int q = 0; q < 8; ++q) acc[j * 8 + q] += a * bf2f((u16)v[q]);
    }
  }
#pragma unroll
  for (int j = 0; j < 4; ++j) {
    int c0 = (tid + j * 256) * 8;
    short8 ov;
#pragma unroll
    for (int q = 0; q < 8; ++q) ov[q] = (short)f2bf(acc[j * 8 + q] + bias[c0 + q]);
    *reinterpret_cast<short8*>(out + (size_t)n * 8192 + c0) = ov;
  }
}

// ---------------- mean pool over sorted batch --------------------------------
__global__ __launch_bounds__(256) void pool_mean(
    const u16* __restrict__ hf, const int* __restrict__ batch,
    u16* __restrict__ g, int Nn)
{
  int gid = blockIdx.x, tid = threadIdx.x;
  int s1, s2;
  { int l = 0, h = Nn; while (l < h) { int m = (l + h) >> 1; if (batch[m] < gid) l = m + 1; else h = m; } s1 = l; }
  { int l = 0, h = Nn; while (l < h) { int m = (l + h) >> 1; if (batch[m] < gid + 1) l = m + 1; else h = m; } s2 = l; }
  float inv = 1.f / fmaxf((float)(s2 - s1), 1.f);
  float acc[8];
#pragma unroll
  for (int q = 0; q < 8; ++q) acc[q] = 0.f;
  for (int r = s1; r < s2; ++r) {
    short8 v = *reinterpret_cast<const short8*>(hf + (size_t)r * 2048 + tid * 8);
#pragma unroll
    for (int q = 0; q < 8; ++q) acc[q] += bf2f((u16)v[q]);
  }
  short8 ov;
#pragma unroll
  for (int q = 0; q < 8; ++q) ov[q] = (short)f2bf(acc[q] * inv);
  *reinterpret_cast<short8*>(g + (size_t)gid * 2048 + tid * 8) = ov;
}

// ---------------- layernorm over 768 ----------------------------------------
__global__ __launch_bounds__(256) void layernorm_768(
    const float* __restrict__ x, const float* __restrict__ gam,
    const float* __restrict__ bet, float* __restrict__ out)
{
  int row = blockIdx.x, tid = threadIdx.x, lane = tid & 63, w = tid >> 6;
  __shared__ float sh[8];
  float v0 = x[row * 768 + tid];
  float v1 = x[row * 768 + 256 + tid];
  float v2 = x[row * 768 + 512 + tid];
  float s = v0 + v1 + v2;
  for (int off = 32; off; off >>= 1) s += __shfl_down(s, off);
  if (lane == 0) sh[w] = s;
  __syncthreads();
  if (tid == 0) sh[4] = (sh[0] + sh[1] + sh[2] + sh[3]) / 768.f;
  __syncthreads();
  float mu = sh[4];
  float d0 = v0 - mu, d1 = v1 - mu, d2 = v2 - mu;
  float q = d0 * d0 + d1 * d1 + d2 * d2;
  for (int off = 32; off; off >>= 1) q += __shfl_down(q, off);
  if (lane == 0) sh[w] = q;
  __syncthreads();
  if (tid == 0) sh[5] = rsqrtf((sh[0] + sh[1] + sh[2] + sh[3]) / 768.f + 1e-5f);
  __syncthreads();
  float rstd = sh[5];
  out[row * 768 + tid]       = d0 * rstd * gam[tid]       + bet[tid];
  out[row * 768 + 256 + tid] = d1 * rstd * gam[256 + tid] + bet[256 + tid];
  out[row * 768 + 512 + tid] = d2 * rstd * gam[512 + tid] + bet[512 + tid];
}

// ============================================================================
extern "C" void kernel_launch(void* const* d_in, const int* in_sizes, int n_in,
                              void* d_out, int out_size, void* d_ws, size_t ws_size,
                              hipStream_t stream)
{
  const float* x     = (const float*)d_in[0];
  const int*   ei    = (const int*)d_in[1];
  const int*   batch = (const int*)d_in[2];
  const float* W[3]   = {(const float*)d_in[3], (const float*)d_in[9],  (const float*)d_in[15]};
  const float* asr[3] = {(const float*)d_in[4], (const float*)d_in[10], (const float*)d_in[16]};
  const float* ads[3] = {(const float*)d_in[5], (const float*)d_in[11], (const float*)d_in[17]};
  const float* bc[3]  = {(const float*)d_in[6], (const float*)d_in[12], (const float*)d_in[18]};
  const float* Wh[3]  = {(const float*)d_in[7], (const float*)d_in[13], (const float*)d_in[19]};
  const float* bh[3]  = {(const float*)d_in[8], (const float*)d_in[14], (const float*)d_in[20]};
  const float* Wm1 = (const float*)d_in[21];
  const float* bm1 = (const float*)d_in[22];
  const float* Wm2 = (const float*)d_in[23];
  const float* bm2 = (const float*)d_in[24];
  const float* lng = (const float*)d_in[25];
  const float* lnb = (const float*)d_in[26];
  float* out = (float*)d_out;

  int Nn = in_sizes[2];        // 5000
  int E  = in_sizes[1] / 2;    // 15000
  int ET = E + Nn;             // + self loops

  char* base = (char*)d_ws;
  size_t off = 0;
  auto alloc = [&](size_t b) -> char* { char* p = base + off; off = (off + b + 255) & ~(size_t)255; return p; };
  u16*  xb    = (u16*)alloc((size_t)Nn * 320 * 2);
  u16*  Wt    = (u16*)alloc((size_t)8192 * 2048 * 2);
  u16*  Wht   = (u16*)alloc((size_t)8192 * 2048 * 2);
  u16*  hb    = (u16*)alloc((size_t)Nn * 8192 * 2);
  u16*  ob    = (u16*)alloc((size_t)Nn * 8192 * 2);
  u16*  xlb   = (u16*)alloc((size_t)Nn * 2048 * 2);
  float* a_s  = (float*)alloc((size_t)Nn * 4 * 4);
  float* a_d  = (float*)alloc((size_t)Nn * 4 * 4);
  float* alpha= (float*)alloc((size_t)ET * 4 * 4);
  int*  deg   = (int*)alloc((size_t)(Nn + 1) * 4);
  int*  rowst = (int*)alloc((size_t)(Nn + 1) * 4);
  int*  cursor= (int*)alloc((size_t)(Nn + 1) * 4);
  int*  srcs  = (int*)alloc((size_t)ET * 4);
  u16*  g     = (u16*)alloc((size_t)128 * 2048 * 2);
  u16*  g2    = (u16*)alloc((size_t)128 * 2048 * 2);
  float* preln= (float*)alloc((size_t)128 * 768 * 4);

  // ---- CSR by dst (self loops appended) ----
  zero_int<<<(Nn + 255) / 256, 256, 0, stream>>>(deg, Nn);
  count_deg<<<(ET + 255) / 256, 256, 0, stream>>>(ei, E, Nn, deg);
  scan_deg<<<1, 256, 0, stream>>>(deg, rowst, cursor, Nn);
  scatter_edges<<<(ET + 255) / 256, 256, 0, stream>>>(ei, E, Nn, cursor, srcs);

  // ---- input cast (pad K 300->320) ----
  cast_pad<<<(Nn * 320 + 255) / 256, 256, 0, stream>>>(x, xb, Nn, 300, 320);

  const u16* act = xb;
  int mtiles = (Nn + 127) / 128;
  for (int l = 0; l < 3; ++l) {
    int Kp = (l == 0) ? 320 : 2048;
    transpose_cast<<<dim3(Kp / 32, 8192 / 32), 256, 0, stream>>>(W[l], Wt, (l == 0) ? 300 : 2048, 8192, Kp);
    gemm_bt<<<dim3(64, mtiles), 256, 0, stream>>>(act, Wt, nullptr, hb, nullptr, Nn, 8192, Kp, 0);
    attn_scores<<<Nn, 256, 0, stream>>>(hb, asr[l], ads[l], a_s, a_d);
    edge_softmax<<<(Nn * 4 + 255) / 256, 256, 0, stream>>>(rowst, srcs, a_s, a_d, alpha, Nn);
    aggregate<<<Nn, 256, 0, stream>>>(hb, alpha, rowst, srcs, bc[l], ob);
    transpose_cast<<<dim3(8192 / 32, 2048 / 32), 256, 0, stream>>>(Wh[l], Wht, 8192, 2048, 8192);
    gemm_bt<<<dim3(16, mtiles), 256, 0, stream>>>(ob, Wht, nullptr, xlb, bh[l], Nn, 2048, 8192, (l < 2) ? 1 : 0);
    act = xlb;
  }

  // ---- mean pool + MLP + LN ----
  pool_mean<<<128, 256, 0, stream>>>(xlb, batch, g, Nn);
  transpose_cast<<<dim3(2048 / 32, 2048 / 32), 256, 0, stream>>>(Wm1, Wt, 2048, 2048, 2048);
  gemm_bt<<<dim3(16, 1), 256, 0, stream>>>(g, Wt, nullptr, g2, bm1, 128, 2048, 2048, 1);
  transpose_cast<<<dim3(2048 / 32, 768 / 32), 256, 0, stream>>>(Wm2, Wht, 2048, 768, 2048);
  gemm_bt<<<dim3(6, 1), 256, 0, stream>>>(g2, Wht, preln, nullptr, bm2, 128, 768, 2048, 0);
  layernorm_768<<<128, 256, 0, stream>>>(preln, lng, lnb, out);
}

// Round 2
// 1944.146 us; speedup vs baseline: 1.0708x; 1.0708x over previous
//
#include <hip/hip_runtime.h>

typedef unsigned short u16;
typedef __attribute__((ext_vector_type(8))) short short8;
typedef __attribute__((ext_vector_type(4))) float f32x4;

__device__ inline u16 f2bf(float f){
  unsigned int u = __builtin_bit_cast(unsigned int, f);
  u += 0x7fffu + ((u >> 16) & 1u);
  return (u16)(u >> 16);
}
__device__ inline float bf2f(u16 h){
  unsigned int u = ((unsigned int)h) << 16;
  return __builtin_bit_cast(float, u);
}

typedef __attribute__((address_space(1))) const void* as1_t;
typedef __attribute__((address_space(3))) void* as3_t;
__device__ __forceinline__ void gload16(const u16* g, u16* l) {
  __builtin_amdgcn_global_load_lds((as1_t)g, (as3_t)l, 16, 0, 0);
}

// ---------------- weight transpose + cast:  W[K,N] f32 -> Wt[N,Kpad] bf16 ----
__global__ __launch_bounds__(256) void transpose_cast(
    const float* __restrict__ W, u16* __restrict__ Wt, int K, int N, int Kpad)
{
  __shared__ float tile[32][33];
  int k0 = blockIdx.x * 32, n0 = blockIdx.y * 32;
  int tx = threadIdx.x & 31, ty = threadIdx.x >> 5;   // ty 0..7
#pragma unroll
  for (int i = 0; i < 4; ++i) {
    int k = k0 + ty + i * 8;
    float v = 0.f;
    if (k < K && (n0 + tx) < N) v = W[(size_t)k * N + n0 + tx];
    tile[ty + i * 8][tx] = v;
  }
  __syncthreads();
#pragma unroll
  for (int i = 0; i < 4; ++i) {
    int nn = n0 + ty + i * 8;
    if (nn < N) Wt[(size_t)nn * Kpad + k0 + tx] = f2bf(tile[tx][ty + i * 8]);
  }
}

// ---------------- x cast with K padding -------------------------------------
__global__ void cast_pad(const float* __restrict__ x, u16* __restrict__ xb,
                         int R, int C, int Cp)
{
  int i = blockIdx.x * 256 + threadIdx.x;
  if (i >= R * Cp) return;
  int r = i / Cp, c = i % Cp;
  xb[i] = f2bf(c < C ? x[(size_t)r * C + c] : 0.f);
}

// ---------------- bf16 MFMA GEMM: C[M,N] = A[M,K] @ Bt[N,K]^T ---------------
// m97 structure: global_load_lds width=16 direct-to-LDS, linear [128][32] tiles.
// A,Bt row-major bf16, row stride K (multiple of 32). N multiple of 128.
// A-rows beyond M may be read (garbage) but only affect discarded output rows.
__global__ __launch_bounds__(256) void gemm_bt(
    const u16* __restrict__ A, const u16* __restrict__ B,
    float* __restrict__ Cf, u16* __restrict__ Cb,
    const float* __restrict__ bias, int M, int N, int K, int relu)
{
  __shared__ alignas(16) u16 As[128 * 32];
  __shared__ alignas(16) u16 Bs[128 * 32];
  int tid = threadIdx.x;
  int wave = tid >> 6, lane = tid & 63;
  int wr = wave >> 1, wc = wave & 1;
  int tile_m = blockIdx.y * 128, tile_n = blockIdx.x * 128;

  // DMA staging: wave w writes LDS bytes [i*4096 + w*1024 + lane*16].
  // LDS row = byte/64 -> row = i*64 + w*16 + lane/4, col = (lane&3)*8.
  int sr = wave * 16 + (lane >> 2);
  int sc = (lane & 3) * 8;
  const u16* gA0 = A + (size_t)(tile_m + sr) * K + sc;
  const u16* gA1 = A + (size_t)(tile_m + 64 + sr) * K + sc;
  const u16* gB0 = B + (size_t)(tile_n + sr) * K + sc;
  const u16* gB1 = B + (size_t)(tile_n + 64 + sr) * K + sc;
  u16* lA0 = &As[wave * 512];          // wave*1024 bytes
  u16* lA1 = &As[2048 + wave * 512];   // +4096 bytes
  u16* lB0 = &Bs[wave * 512];
  u16* lB1 = &Bs[2048 + wave * 512];

  f32x4 acc[4][4];
#pragma unroll
  for (int mi = 0; mi < 4; ++mi)
#pragma unroll
    for (int ni = 0; ni < 4; ++ni) { f32x4 z = {0.f,0.f,0.f,0.f}; acc[mi][ni] = z; }

  int lrow = lane & 15, lk = (lane >> 4) * 8;

  for (int k0 = 0; k0 < K; k0 += 32) {
    gload16(gA0 + k0, lA0);
    gload16(gA1 + k0, lA1);
    gload16(gB0 + k0, lB0);
    gload16(gB1 + k0, lB1);
    __syncthreads();   // compiler emits vmcnt(0) drain before s_barrier
    short8 af[4], bfr[4];
#pragma unroll
    for (int mi = 0; mi < 4; ++mi)
      af[mi] = *reinterpret_cast<const short8*>(&As[(wr * 64 + mi * 16 + lrow) * 32 + lk]);
#pragma unroll
    for (int ni = 0; ni < 4; ++ni)
      bfr[ni] = *reinterpret_cast<const short8*>(&Bs[(wc * 64 + ni * 16 + lrow) * 32 + lk]);
#pragma unroll
    for (int mi = 0; mi < 4; ++mi)
#pragma unroll
      for (int ni = 0; ni < 4; ++ni)
        acc[mi][ni] = __builtin_amdgcn_mfma_f32_16x16x32_bf16(af[mi], bfr[ni], acc[mi][ni], 0, 0, 0);
    __syncthreads();
  }

  int rquad = (lane >> 4) * 4;
#pragma unroll
  for (int mi = 0; mi < 4; ++mi)
#pragma unroll
    for (int ni = 0; ni < 4; ++ni) {
      int col = tile_n + wc * 64 + ni * 16 + lrow;
      float bv = bias ? bias[col] : 0.f;
#pragma unroll
      for (int j = 0; j < 4; ++j) {
        int row = tile_m + wr * 64 + mi * 16 + rquad + j;
        if (row < M) {
          float v = acc[mi][ni][j] + bv;
          if (relu) v = fmaxf(v, 0.f);
          if (Cb) Cb[(size_t)row * N + col] = f2bf(v);
          else    Cf[(size_t)row * N + col] = v;
        }
      }
    }
}

// ---------------- attention scores: a_src/a_dst [N,4] -----------------------
__global__ __launch_bounds__(256) void attn_scores(
    const u16* __restrict__ h, const float* __restrict__ asrc,
    const float* __restrict__ adst, float* __restrict__ a_s, float* __restrict__ a_d)
{
  int n = blockIdx.x;
  int hh = threadIdx.x >> 6, lane = threadIdx.x & 63;
  const u16* hr = h + (size_t)n * 8192 + hh * 2048;
  const float* as = asrc + hh * 2048;
  const float* ad = adst + hh * 2048;
  float ssum = 0.f, dsum = 0.f;
#pragma unroll
  for (int i = 0; i < 4; ++i) {
    int c = lane * 8 + i * 512;
    short8 v = *reinterpret_cast<const short8*>(hr + c);
#pragma unroll
    for (int j = 0; j < 8; ++j) {
      float f = bf2f((u16)v[j]);
      ssum += f * as[c + j];
      dsum += f * ad[c + j];
    }
  }
  for (int off = 32; off; off >>= 1) {
    ssum += __shfl_down(ssum, off);
    dsum += __shfl_down(dsum, off);
  }
  if (lane == 0) { a_s[n * 4 + hh] = ssum; a_d[n * 4 + hh] = dsum; }
}

// ---------------- CSR build --------------------------------------------------
__global__ void zero_int(int* p, int n){ int i = blockIdx.x*256+threadIdx.x; if (i < n) p[i] = 0; }

__global__ void count_deg(const int* __restrict__ ei, int E, int Nn, int* __restrict__ deg){
  int e = blockIdx.x*256+threadIdx.x; if (e >= E + Nn) return;
  int d = (e < E) ? ei[E + e] : (e - E);
  atomicAdd(&deg[d], 1);
}

__global__ void scan_deg(const int* __restrict__ deg, int* __restrict__ row_st,
                         int* __restrict__ cursor, int Nn){
  __shared__ int partial[256];
  int tid = threadIdx.x;
  int chunk = (Nn + 255) / 256;
  int start = tid * chunk;
  int sum = 0;
  for (int i = 0; i < chunk; ++i) { int idx = start + i; if (idx < Nn) sum += deg[idx]; }
  partial[tid] = sum;
  __syncthreads();
  if (tid == 0) { int acc = 0; for (int i = 0; i < 256; ++i) { int t = partial[i]; partial[i] = acc; acc += t; } }
  __syncthreads();
  int acc = partial[tid];
  for (int i = 0; i < chunk; ++i) {
    int idx = start + i;
    if (idx < Nn) { row_st[idx] = acc; cursor[idx] = acc; acc += deg[idx]; }
  }
  if (tid == 255) row_st[Nn] = acc;
}

__global__ void scatter_edges(const int* __restrict__ ei, int E, int Nn,
                              int* __restrict__ cursor, int* __restrict__ srcs){
  int e = blockIdx.x*256+threadIdx.x; if (e >= E + Nn) return;
  int s = (e < E) ? ei[e]     : (e - E);
  int d = (e < E) ? ei[E + e] : (e - E);
  int pos = atomicAdd(&cursor[d], 1);
  srcs[pos] = s;
}

// ---------------- per-(node,head) edge softmax -------------------------------
__global__ void edge_softmax(const int* __restrict__ row_st, const int* __restrict__ srcs,
                             const float* __restrict__ a_s, const float* __restrict__ a_d,
                             float* __restrict__ alpha, int Nn){
  int t = blockIdx.x*256+threadIdx.x;
  if (t >= Nn * 4) return;
  int n = t >> 2, hh = t & 3;
  int b = row_st[n], e = row_st[n + 1];
  float ad = a_d[n * 4 + hh];
  float m = -1e30f;
  for (int p = b; p < e; ++p) {
    float x = a_s[srcs[p] * 4 + hh] + ad;
    x = x > 0.f ? x : 0.2f * x;
    alpha[p * 4 + hh] = x;
    m = fmaxf(m, x);
  }
  float ssum = 0.f;
  for (int p = b; p < e; ++p) {
    float ex = expf(alpha[p * 4 + hh] - m);
    alpha[p * 4 + hh] = ex;
    ssum += ex;
  }
  float inv = 1.f / (ssum + 1e-16f);
  for (int p = b; p < e; ++p) alpha[p * 4 + hh] *= inv;
}

// ---------------- aggregation: out[n] = sum alpha*h[src] + bias (bf16 out) ---
__global__ __launch_bounds__(256) void aggregate(
    const u16* __restrict__ h, const float* __restrict__ alpha,
    const int* __restrict__ row_st, const int* __restrict__ srcs,
    const float* __restrict__ bias, u16* __restrict__ out)
{
  int n = blockIdx.x, tid = threadIdx.x;
  float acc[32];
#pragma unroll
  for (int i = 0; i < 32; ++i) acc[i] = 0.f;
  int b = row_st[n], e = row_st[n + 1];
  for (int p = b; p < e; ++p) {
    int s = srcs[p];
    const u16* hr = h + (size_t)s * 8192;
    float al[4];
#pragma unroll
    for (int j = 0; j < 4; ++j) al[j] = alpha[p * 4 + j];
#pragma unroll
    for (int j = 0; j < 4; ++j) {
      short8 v = *reinterpret_cast<const short8*>(hr + (tid + j * 256) * 8);
      float a = al[j];
#pragma unroll
      for (int q = 0; q < 8; ++q) acc[j * 8 + q] += a * bf2f((u16)v[q]);
    }
  }
#pragma unroll
  for (int j = 0; j < 4; ++j) {
    int c0 = (tid + j * 256) * 8;
    short8 ov;
#pragma unroll
    for (int q = 0; q < 8; ++q) ov[q] = (short)f2bf(acc[j * 8 + q] + bias[c0 + q]);
    *reinterpret_cast<short8*>(out + (size_t)n * 8192 + c0) = ov;
  }
}

// ---------------- mean pool over sorted batch --------------------------------
__global__ __launch_bounds__(256) void pool_mean(
    const u16* __restrict__ hf, const int* __restrict__ batch,
    u16* __restrict__ g, int Nn)
{
  int gid = blockIdx.x, tid = threadIdx.x;
  int s1, s2;
  { int l = 0, h = Nn; while (l < h) { int m = (l + h) >> 1; if (batch[m] < gid) l = m + 1; else h = m; } s1 = l; }
  { int l = 0, h = Nn; while (l < h) { int m = (l + h) >> 1; if (batch[m] < gid + 1) l = m + 1; else h = m; } s2 = l; }
  float inv = 1.f / fmaxf((float)(s2 - s1), 1.f);
  float acc[8];
#pragma unroll
  for (int q = 0; q < 8; ++q) acc[q] = 0.f;
  for (int r = s1; r < s2; ++r) {
    short8 v = *reinterpret_cast<const short8*>(hf + (size_t)r * 2048 + tid * 8);
#pragma unroll
    for (int q = 0; q < 8; ++q) acc[q] += bf2f((u16)v[q]);
  }
  short8 ov;
#pragma unroll
  for (int q = 0; q < 8; ++q) ov[q] = (short)f2bf(acc[q] * inv);
  *reinterpret_cast<short8*>(g + (size_t)gid * 2048 + tid * 8) = ov;
}

// ---------------- layernorm over 768 ----------------------------------------
__global__ __launch_bounds__(256) void layernorm_768(
    const float* __restrict__ x, const float* __restrict__ gam,
    const float* __restrict__ bet, float* __restrict__ out)
{
  int row = blockIdx.x, tid = threadIdx.x, lane = tid & 63, w = tid >> 6;
  __shared__ float sh[8];
  float v0 = x[row * 768 + tid];
  float v1 = x[row * 768 + 256 + tid];
  float v2 = x[row * 768 + 512 + tid];
  float s = v0 + v1 + v2;
  for (int off = 32; off; off >>= 1) s += __shfl_down(s, off);
  if (lane == 0) sh[w] = s;
  __syncthreads();
  if (tid == 0) sh[4] = (sh[0] + sh[1] + sh[2] + sh[3]) / 768.f;
  __syncthreads();
  float mu = sh[4];
  float d0 = v0 - mu, d1 = v1 - mu, d2 = v2 - mu;
  float q = d0 * d0 + d1 * d1 + d2 * d2;
  for (int off = 32; off; off >>= 1) q += __shfl_down(q, off);
  if (lane == 0) sh[w] = q;
  __syncthreads();
  if (tid == 0) sh[5] = rsqrtf((sh[0] + sh[1] + sh[2] + sh[3]) / 768.f + 1e-5f);
  __syncthreads();
  float rstd = sh[5];
  out[row * 768 + tid]       = d0 * rstd * gam[tid]       + bet[tid];
  out[row * 768 + 256 + tid] = d1 * rstd * gam[256 + tid] + bet[256 + tid];
  out[row * 768 + 512 + tid] = d2 * rstd * gam[512 + tid] + bet[512 + tid];
}

// ============================================================================
extern "C" void kernel_launch(void* const* d_in, const int* in_sizes, int n_in,
                              void* d_out, int out_size, void* d_ws, size_t ws_size,
                              hipStream_t stream)
{
  const float* x     = (const float*)d_in[0];
  const int*   ei    = (const int*)d_in[1];
  const int*   batch = (const int*)d_in[2];
  const float* W[3]   = {(const float*)d_in[3], (const float*)d_in[9],  (const float*)d_in[15]};
  const float* asr[3] = {(const float*)d_in[4], (const float*)d_in[10], (const float*)d_in[16]};
  const float* ads[3] = {(const float*)d_in[5], (const float*)d_in[11], (const float*)d_in[17]};
  const float* bc[3]  = {(const float*)d_in[6], (const float*)d_in[12], (const float*)d_in[18]};
  const float* Wh[3]  = {(const float*)d_in[7], (const float*)d_in[13], (const float*)d_in[19]};
  const float* bh[3]  = {(const float*)d_in[8], (const float*)d_in[14], (const float*)d_in[20]};
  const float* Wm1 = (const float*)d_in[21];
  const float* bm1 = (const float*)d_in[22];
  const float* Wm2 = (const float*)d_in[23];
  const float* bm2 = (const float*)d_in[24];
  const float* lng = (const float*)d_in[25];
  const float* lnb = (const float*)d_in[26];
  float* out = (float*)d_out;

  int Nn = in_sizes[2];        // 5000
  int E  = in_sizes[1] / 2;    // 15000
  int ET = E + Nn;             // + self loops

  char* base = (char*)d_ws;
  size_t off = 0;
  auto alloc = [&](size_t b) -> char* { char* p = base + off; off = (off + b + 255) & ~(size_t)255; return p; };
  u16*  xb    = (u16*)alloc((size_t)Nn * 320 * 2);
  u16*  Wt    = (u16*)alloc((size_t)8192 * 2048 * 2);
  u16*  Wht   = (u16*)alloc((size_t)8192 * 2048 * 2);
  u16*  hb    = (u16*)alloc((size_t)Nn * 8192 * 2);
  u16*  ob    = (u16*)alloc((size_t)Nn * 8192 * 2);
  u16*  xlb   = (u16*)alloc((size_t)Nn * 2048 * 2);
  float* a_s  = (float*)alloc((size_t)Nn * 4 * 4);
  float* a_d  = (float*)alloc((size_t)Nn * 4 * 4);
  float* alpha= (float*)alloc((size_t)ET * 4 * 4);
  int*  deg   = (int*)alloc((size_t)(Nn + 1) * 4);
  int*  rowst = (int*)alloc((size_t)(Nn + 1) * 4);
  int*  cursor= (int*)alloc((size_t)(Nn + 1) * 4);
  int*  srcs  = (int*)alloc((size_t)ET * 4);
  u16*  g     = (u16*)alloc((size_t)128 * 2048 * 2);
  u16*  g2    = (u16*)alloc((size_t)128 * 2048 * 2);
  float* preln= (float*)alloc((size_t)128 * 768 * 4);

  // ---- CSR by dst (self loops appended) ----
  zero_int<<<(Nn + 255) / 256, 256, 0, stream>>>(deg, Nn);
  count_deg<<<(ET + 255) / 256, 256, 0, stream>>>(ei, E, Nn, deg);
  scan_deg<<<1, 256, 0, stream>>>(deg, rowst, cursor, Nn);
  scatter_edges<<<(ET + 255) / 256, 256, 0, stream>>>(ei, E, Nn, cursor, srcs);

  // ---- input cast (pad K 300->320) ----
  cast_pad<<<(Nn * 320 + 255) / 256, 256, 0, stream>>>(x, xb, Nn, 300, 320);

  const u16* act = xb;
  int mtiles = (Nn + 127) / 128;
  for (int l = 0; l < 3; ++l) {
    int Kp = (l == 0) ? 320 : 2048;
    transpose_cast<<<dim3(Kp / 32, 8192 / 32), 256, 0, stream>>>(W[l], Wt, (l == 0) ? 300 : 2048, 8192, Kp);
    gemm_bt<<<dim3(64, mtiles), 256, 0, stream>>>(act, Wt, nullptr, hb, nullptr, Nn, 8192, Kp, 0);
    attn_scores<<<Nn, 256, 0, stream>>>(hb, asr[l], ads[l], a_s, a_d);
    edge_softmax<<<(Nn * 4 + 255) / 256, 256, 0, stream>>>(rowst, srcs, a_s, a_d, alpha, Nn);
    aggregate<<<Nn, 256, 0, stream>>>(hb, alpha, rowst, srcs, bc[l], ob);
    transpose_cast<<<dim3(8192 / 32, 2048 / 32), 256, 0, stream>>>(Wh[l], Wht, 8192, 2048, 8192);
    gemm_bt<<<dim3(16, mtiles), 256, 0, stream>>>(ob, Wht, nullptr, xlb, bh[l], Nn, 2048, 8192, (l < 2) ? 1 : 0);
    act = xlb;
  }

  // ---- mean pool + MLP + LN ----
  pool_mean<<<128, 256, 0, stream>>>(xlb, batch, g, Nn);
  transpose_cast<<<dim3(2048 / 32, 2048 / 32), 256, 0, stream>>>(Wm1, Wt, 2048, 2048, 2048);
  gemm_bt<<<dim3(16, 1), 256, 0, stream>>>(g, Wt, nullptr, g2, bm1, 128, 2048, 2048, 1);
  transpose_cast<<<dim3(2048 / 32, 768 / 32), 256, 0, stream>>>(Wm2, Wht, 2048, 768, 2048);
  gemm_bt<<<dim3(6, 1), 256, 0, stream>>>(g2, Wht, preln, nullptr, bm2, 128, 768, 2048, 0);
  layernorm_768<<<128, 256, 0, stream>>>(preln, lng, lnb, out);
}